// Round 1
// baseline (772.180 us; speedup 1.0000x reference)
//
#include <hip/hip_runtime.h>
#include <math.h>

#define EPSF 1e-8f
#define ATT_NORM 2.0f

constexpr int H = 8;
constexpr int D = 16;
constexpr int N_NODES_C = 50000;

// Pass 1: nj = ||x_j[e,h,:]|| + eps ; scatter-max into node_max[index[e]*H + h].
// node_max holds float bits as uint; all nj > 0 so unsigned-int max == float max,
// and a zeroed buffer is exactly the 0.0f base of the reference segment-max.
__global__ __launch_bounds__(256) void nj_scatter_max(
    const float* __restrict__ x_j,
    const int* __restrict__ index,
    unsigned int* __restrict__ node_max,
    int EH)
{
    int t = blockIdx.x * 256 + threadIdx.x;
    if (t >= EH) return;
    const float4* p = reinterpret_cast<const float4*>(x_j) + (size_t)t * (D / 4);
    float s = 0.f;
#pragma unroll
    for (int i = 0; i < D / 4; ++i) {
        float4 v = p[i];
        s = fmaf(v.x, v.x, s);
        s = fmaf(v.y, v.y, s);
        s = fmaf(v.z, v.z, s);
        s = fmaf(v.w, v.w, s);
    }
    float nj = sqrtf(s) + EPSF;
    int e = t >> 3;   // t / H
    int h = t & 7;    // t % H
    int idx = index[e];
    atomicMax(&node_max[idx * H + h], __float_as_uint(nj));
}

// Pass 2: ni = ||x_i[e,h,:]|| + eps ; denom = 2*(ni + (seg_max + eps)) + eps ;
// out = clip(e_ij / denom, -10, 10)
__global__ __launch_bounds__(256) void lipschitz_out(
    const float* __restrict__ e_ij,
    const float* __restrict__ x_i,
    const int* __restrict__ index,
    const unsigned int* __restrict__ node_max,
    float* __restrict__ out,
    int EH)
{
    int t = blockIdx.x * 256 + threadIdx.x;
    if (t >= EH) return;
    const float4* p = reinterpret_cast<const float4*>(x_i) + (size_t)t * (D / 4);
    float s = 0.f;
#pragma unroll
    for (int i = 0; i < D / 4; ++i) {
        float4 v = p[i];
        s = fmaf(v.x, v.x, s);
        s = fmaf(v.y, v.y, s);
        s = fmaf(v.z, v.z, s);
        s = fmaf(v.w, v.w, s);
    }
    float ni = sqrtf(s) + EPSF;
    int e = t >> 3;
    int h = t & 7;
    int idx = index[e];
    float m = __uint_as_float(node_max[idx * H + h]) + EPSF;
    float denom = ATT_NORM * (ni + m) + EPSF;
    float r = e_ij[t] / denom;
    out[t] = fminf(10.0f, fmaxf(-10.0f, r));
}

extern "C" void kernel_launch(void* const* d_in, const int* in_sizes, int n_in,
                              void* d_out, int out_size, void* d_ws, size_t ws_size,
                              hipStream_t stream)
{
    const float* e_ij = (const float*)d_in[0];   // [E, H]
    const float* x_i  = (const float*)d_in[1];   // [E, H, D]
    const float* x_j  = (const float*)d_in[2];   // [E, H, D]
    const int*   index = (const int*)d_in[3];    // [E] (int32 on device)

    float* out = (float*)d_out;                  // [E, H]
    unsigned int* node_max = (unsigned int*)d_ws; // [N_NODES, H] float-as-uint

    const int EH = in_sizes[0];                  // E * H = 6.4M

    // Zero the segment-max base (ws is poisoned 0xAA before every launch).
    hipMemsetAsync(node_max, 0, (size_t)N_NODES_C * H * sizeof(unsigned int), stream);

    const int block = 256;
    const int grid = (EH + block - 1) / block;

    nj_scatter_max<<<grid, block, 0, stream>>>(x_j, index, node_max, EH);
    lipschitz_out<<<grid, block, 0, stream>>>(e_ij, x_i, index, node_max, out, EH);
}